// Round 1
// baseline (3693.445 us; speedup 1.0000x reference)
//
#include <hip/hip_runtime.h>
#include <cstddef>

#define N_NODES 10000
#define KNBR 32
#define HDIM 128
#define NHEADS 8

// ---------------- helpers ----------------

// tanh-approximate gelu, matching jax.nn.gelu(approximate=True)
__device__ __forceinline__ float gelu_f(float x) {
  float a = 0.7978845608028654f * fmaf(0.044715f * x, x * x, x);
  float e = __expf(2.0f * a);               // e=inf -> 2/(e+1)=0 -> x ; e=0 -> -> 0
  return 0.5f * x * (2.0f - 2.0f / (e + 1.0f));
}

// out[k][col] += sum_e in[k][e] * W[e*wstride + col], for this thread's NK rows
// in: LDS rows (wave-uniform broadcast reads); W: global, coalesced across lanes.
template <int IN, int NK>
__device__ __forceinline__ void mm_rows(float* acc, const float* in, int istride,
                                        int k0, int kstep,
                                        const float* __restrict__ W, int wstride,
                                        int col) {
  const float* wp = W + col;
#pragma unroll 2
  for (int e = 0; e < IN; e += 4) {
    float w0 = wp[0];
    float w1 = wp[wstride];
    float w2 = wp[2 * wstride];
    float w3 = wp[3 * wstride];
    wp += 4 * wstride;
#pragma unroll
    for (int kk = 0; kk < NK; ++kk) {
      const float4 x = *(const float4*)(in + (k0 + kk * kstep) * istride + e);
      acc[kk] = fmaf(x.x, w0, acc[kk]);
      acc[kk] = fmaf(x.y, w1, acc[kk]);
      acc[kk] = fmaf(x.z, w2, acc[kk]);
      acc[kk] = fmaf(x.w, w3, acc[kk]);
    }
  }
}

// LayerNorm of 32 rows of 128 (biased var, eps 1e-5). scr needs 576 floats.
// Must be called by all 256 threads (contains barriers).
__device__ __forceinline__ void ln_rows32(const float* in, float* out,
                                          const float* __restrict__ g,
                                          const float* __restrict__ be,
                                          float* scr, int tid) {
  {
    int r = tid >> 3, j = tid & 7;
    float s = 0.f, s2 = 0.f;
    const float* row = in + r * 128 + j * 16;
#pragma unroll
    for (int i = 0; i < 16; ++i) {
      float x = row[i];
      s += x;
      s2 = fmaf(x, x, s2);
    }
    scr[r * 8 + j] = s;
    scr[256 + r * 8 + j] = s2;
  }
  __syncthreads();
  if (tid < 32) {
    float s = 0.f, s2 = 0.f;
#pragma unroll
    for (int j = 0; j < 8; ++j) {
      s += scr[tid * 8 + j];
      s2 += scr[256 + tid * 8 + j];
    }
    float m = s * (1.f / 128.f);
    float v = fmaf(-m, m, s2 * (1.f / 128.f));
    scr[512 + tid] = m;
    scr[544 + tid] = rsqrtf(v + 1e-5f);
  }
  __syncthreads();
  {
    int h = tid & 127, khf = tid >> 7;
    float gg = g[h], bb = be[h];
#pragma unroll
    for (int kk = 0; kk < 16; ++kk) {
      int k = khf + kk * 2;
      float m = scr[512 + k], rs = scr[544 + k];
      out[k * 128 + h] = fmaf((in[k * 128 + h] - m) * rs, gg, bb);
    }
  }
  __syncthreads();  // scr reusable after this
}

// ---------------- kernel 1: LN of node_features -> ws0 ----------------
__global__ __launch_bounds__(256, 2) void ln_in_kernel(
    const float* __restrict__ in, const float* __restrict__ g,
    const float* __restrict__ be, float* __restrict__ out) {
  __shared__ __align__(16) float lds[4096 + 4096 + 576];
  float* A = lds;
  float* B = lds + 4096;
  float* scr = lds + 8192;
  const int tid = threadIdx.x;
  const size_t base = (size_t)blockIdx.x * 32;
  for (int i = tid; i < 1024; i += 256) {
    int r = i >> 5;
    float4 v = make_float4(0.f, 0.f, 0.f, 0.f);
    if (base + r < N_NODES) v = ((const float4*)in)[base * 32 + i];
    ((float4*)A)[i] = v;
  }
  __syncthreads();
  ln_rows32(A, B, g, be, scr, tid);
  for (int i = tid; i < 1024; i += 256) {
    int r = i >> 5;
    if (base + r < N_NODES) ((float4*)out)[base * 32 + i] = ((float4*)B)[i];
  }
}

// ---------------- kernel 2: the fused per-node block ----------------
__global__ __launch_bounds__(256, 2) void egab_main(
    const float* __restrict__ nf, const float* __restrict__ ef,
    const float* __restrict__ ea, const int* __restrict__ nlist,
    const int* __restrict__ nvalid, const float* __restrict__ W_edge,
    const float* __restrict__ b_edge, const float* __restrict__ W_node,
    const float* __restrict__ b_node, const float* __restrict__ W_msg,
    const float* __restrict__ b_msg, const float* __restrict__ W_qkv,
    const float* __restrict__ b_qkv, const float* __restrict__ W_out,
    const float* __restrict__ b_out, const float* __restrict__ g_fe,
    const float* __restrict__ be_fe, const float* __restrict__ We1,
    const float* __restrict__ be1, const float* __restrict__ We2,
    const float* __restrict__ be2, const float* __restrict__ node_hidden,
    float* __restrict__ node_res_out, float* __restrict__ out_edge) {
  // 4 x [32][128] fp32 tiles = exactly 64 KB; everything else aliases dead tiles.
  __shared__ __align__(16) float lds[16384];
  float* L0 = lds;           // edge_hidden -> v -> edge_out -> (ln scratch/hidden lo)
  float* L1 = lds + 4096;    // node_hid -> k -> (hidden hi)
  float* L2 = lds + 8192;    // edge_attr -> msg -> attn scratch -> eh(LN)
  float* L3 = lds + 12288;   // nbr -> q -> ctx -> edge_res
  // attention scratch inside L2 (msg is dead once qkv is built):
  float* S = L2;             // [32][33] padded scores
  float* aq = L2 + 1056;     // [32][17] padded q head slice
  float* ak = L2 + 1600;     // [32][17] padded k head slice
  float* rowinv = L2 + 2144; // [32]

  const int tid = threadIdx.x;
  const int n = blockIdx.x;
  const int nv = nvalid[n];
  const int h = tid & 127;
  const int khf = tid >> 7;  // 0/1 -> rows khf, khf+2, ...

  // ---- stage 1: load edge_attr -> L2, gather neighbors -> L3 ----
  {
    const float4* src = (const float4*)(ea + (size_t)n * 4096);
    float4* dst = (float4*)L2;
    for (int i = tid; i < 1024; i += 256) dst[i] = src[i];
    int k = tid >> 3, j = tid & 7;
    int idx = nlist[n * KNBR + k];
    const float4* s2 = (const float4*)(node_hidden + (size_t)idx * 128 + j * 16);
    float4* d2 = (float4*)(L3 + k * 128 + j * 16);
    d2[0] = s2[0];
    d2[1] = s2[1];
    d2[2] = s2[2];
    d2[3] = s2[3];
  }
  __syncthreads();

  // ---- stage 2a: edge_hidden = gelu(edge_attr @ W_edge + b) -> L0 ----
  {
    float acc[16] = {};
    mm_rows<128, 16>(acc, L2, 128, khf, 2, W_edge, 128, h);
    float b = b_edge[h];
#pragma unroll
    for (int kk = 0; kk < 16; ++kk)
      L0[(khf + kk * 2) * 128 + h] = gelu_f(acc[kk] + b);
  }
  // ---- stage 2b: node_hid = gelu([center,nbr] @ W_node + b) -> L1 ----
  {
    // center part is k-independent: base = sum_e cen[e] * W_node[e][h]
    const float* cen = node_hidden + (size_t)n * 128;  // wave-uniform -> scalar loads
    float base = 0.f;
    const float* wp = W_node + h;
#pragma unroll 2
    for (int e = 0; e < 128; e += 4) {
      float4 c = *(const float4*)(cen + e);
      base = fmaf(c.x, wp[0], base);
      base = fmaf(c.y, wp[128], base);
      base = fmaf(c.z, wp[256], base);
      base = fmaf(c.w, wp[384], base);
      wp += 512;
    }
    float acc[16] = {};
    mm_rows<128, 16>(acc, L3, 128, khf, 2, W_node + 128 * 128, 128, h);
    float b = b_node[h];
#pragma unroll
    for (int kk = 0; kk < 16; ++kk)
      L1[(khf + kk * 2) * 128 + h] = gelu_f(base + acc[kk] + b);
  }
  __syncthreads();

  // ---- stage 3: msg = gelu([edge_hidden, node_hid] @ W_msg + b) -> L2 ----
  {
    float acc[16] = {};
    mm_rows<128, 16>(acc, L0, 128, khf, 2, W_msg, 128, h);
    mm_rows<128, 16>(acc, L1, 128, khf, 2, W_msg + 128 * 128, 128, h);
    float b = b_msg[h];
#pragma unroll
    for (int kk = 0; kk < 16; ++kk)
      L2[(khf + kk * 2) * 128 + h] = gelu_f(acc[kk] + b);
  }
  __syncthreads();

  // ---- stage 4: qkv = msg @ W_qkv + b ; q->L3, k->L1, v->L0 ----
  {
    float acc[16] = {};
    mm_rows<128, 16>(acc, L2, 128, khf, 2, W_qkv, 384, h);
    float b = b_qkv[h];
#pragma unroll
    for (int kk = 0; kk < 16; ++kk) L3[(khf + kk * 2) * 128 + h] = acc[kk] + b;
  }
  {
    float acc[16] = {};
    mm_rows<128, 16>(acc, L2, 128, khf, 2, W_qkv, 384, 128 + h);
    float b = b_qkv[128 + h];
#pragma unroll
    for (int kk = 0; kk < 16; ++kk) L1[(khf + kk * 2) * 128 + h] = acc[kk] + b;
  }
  {
    float acc[16] = {};
    mm_rows<128, 16>(acc, L2, 128, khf, 2, W_qkv, 384, 256 + h);
    float b = b_qkv[256 + h];
#pragma unroll
    for (int kk = 0; kk < 16; ++kk) L0[(khf + kk * 2) * 128 + h] = acc[kk] + b;
  }
  __syncthreads();

  // ---- stage 5: 8-head attention over K=32 (mask: ki >= nv -> -1e9) ----
  // q=L3, k=L1, v=L0 ; ctx overwrites L3 head-slice by head-slice.
  for (int head = 0; head < NHEADS; ++head) {
    const int hofs = head * 16;
    for (int e = tid; e < 512; e += 256) {  // stage padded head slices
      int r = e >> 4, d = e & 15;
      aq[r * 17 + d] = L3[r * 128 + hofs + d];
      ak[r * 17 + d] = L1[r * 128 + hofs + d];
    }
    __syncthreads();
    for (int p = tid; p < 1024; p += 256) {
      int qi = p >> 5, ki = p & 31;
      float s = 0.f;
#pragma unroll
      for (int d = 0; d < 16; ++d) s = fmaf(aq[qi * 17 + d], ak[ki * 17 + d], s);
      s *= 0.25f;  // 1/sqrt(16)
      if (ki >= nv) s = -1e9f;
      S[qi * 33 + ki] = s;
    }
    __syncthreads();
    if (tid < 32) {
      float m = -3.0e38f;
      for (int ki = 0; ki < 32; ++ki) m = fmaxf(m, S[tid * 33 + ki]);
      float sum = 0.f;
      for (int ki = 0; ki < 32; ++ki) {
        float ex = __expf(S[tid * 33 + ki] - m);
        S[tid * 33 + ki] = ex;
        sum += ex;
      }
      rowinv[tid] = 1.f / sum;
    }
    __syncthreads();
    for (int p = tid; p < 512; p += 256) {
      int qi = p >> 4, d = p & 15;
      float c = 0.f;
#pragma unroll
      for (int ki = 0; ki < 32; ++ki)
        c = fmaf(S[qi * 33 + ki], L0[ki * 128 + hofs + d], c);
      L3[qi * 128 + hofs + d] = c * rowinv[qi];  // ctx (q slice already consumed)
    }
    __syncthreads();
  }

  // ---- stage 6: edge_out = ctx @ W_out + b -> L0 (v dead) ----
  {
    float acc[16] = {};
    mm_rows<128, 16>(acc, L3, 128, khf, 2, W_out, 128, h);
    float b = b_out[h];
#pragma unroll
    for (int kk = 0; kk < 16; ++kk) L0[(khf + kk * 2) * 128 + h] = acc[kk] + b;
  }
  __syncthreads();

  // ---- stage 7: residuals; edge_res -> L3 ; node_res -> global ----
  {
    const float4* efr = (const float4*)(ef + (size_t)n * 4096);
    const float4* s0 = (const float4*)L0;
    float4* d3 = (float4*)L3;
    for (int i = tid; i < 1024; i += 256) {
      float4 a = s0[i], b = efr[i];
      d3[i] = make_float4(a.x + b.x, a.y + b.y, a.z + b.z, a.w + b.w);
    }
    if (tid < 128) {
      float s = 0.f;
      for (int k = 0; k < nv; ++k) s += L0[k * 128 + tid];
      node_res_out[(size_t)n * 128 + tid] = s + nf[(size_t)n * 128 + tid];
    }
  }
  __syncthreads();

  // ---- stage 8: eh = LN(edge_res) -> L2 (scratch in dead L0) ----
  ln_rows32(L3, L2, g_fe, be_fe, L0, tid);

  // ---- stage 9: hidden = gelu(eh @ We1 + be1) -> L0∪L1 as [32][256] ----
  {
    float acc[32] = {};
    mm_rows<128, 32>(acc, L2, 128, 0, 1, We1, 256, tid);
    float b = be1[tid];
#pragma unroll
    for (int kk = 0; kk < 32; ++kk) lds[kk * 256 + tid] = gelu_f(acc[kk] + b);
  }
  __syncthreads();

  // ---- stage 10: out = edge_res + hidden @ We2 + be2 -> global ----
  {
    float acc[16] = {};
    mm_rows<256, 16>(acc, lds, 256, khf, 2, We2, 128, h);
    float b = be2[h];
#pragma unroll
    for (int kk = 0; kk < 16; ++kk) {
      int k = khf + kk * 2;
      out_edge[((size_t)n * KNBR + k) * 128 + h] = L3[k * 128 + h] + acc[kk] + b;
    }
  }
}

// ---------------- kernel 3: node FFN (32 nodes/block) ----------------
__global__ __launch_bounds__(256, 2) void node_ffn_kernel(
    const float* __restrict__ nres, const float* __restrict__ g,
    const float* __restrict__ be, const float* __restrict__ Wn1,
    const float* __restrict__ bn1, const float* __restrict__ Wn2,
    const float* __restrict__ bn2, float* __restrict__ out) {
  __shared__ __align__(16) float lds[16384];
  float* HIDb = lds;          // [32][256] (also LN scratch before hidden written)
  float* R = lds + 8192;      // [32][128] residual rows
  float* LNd = lds + 12288;   // [32][128]
  const int tid = threadIdx.x;
  const size_t base = (size_t)blockIdx.x * 32;
  for (int i = tid; i < 1024; i += 256) {
    int r = i >> 5;
    float4 v = make_float4(0.f, 0.f, 0.f, 0.f);
    if (base + r < N_NODES) v = ((const float4*)nres)[base * 32 + i];
    ((float4*)R)[i] = v;
  }
  __syncthreads();
  ln_rows32(R, LNd, g, be, HIDb, tid);  // scratch aliases hidden area (still dead)
  {
    float acc[32] = {};
    mm_rows<128, 32>(acc, LNd, 128, 0, 1, Wn1, 256, tid);
    float b = bn1[tid];
#pragma unroll
    for (int kk = 0; kk < 32; ++kk) HIDb[kk * 256 + tid] = gelu_f(acc[kk] + b);
  }
  __syncthreads();
  {
    const int h = tid & 127, khf = tid >> 7;
    float acc[16] = {};
    mm_rows<256, 16>(acc, HIDb, 256, khf, 2, Wn2, 128, h);
    float b = bn2[h];
#pragma unroll
    for (int kk = 0; kk < 16; ++kk) {
      int k = khf + kk * 2;
      if (base + k < N_NODES)
        out[(base + k) * 128 + h] = R[k * 128 + h] + acc[kk] + b;
    }
  }
}

// ---------------- launch ----------------
extern "C" void kernel_launch(void* const* d_in, const int* in_sizes, int n_in,
                              void* d_out, int out_size, void* d_ws,
                              size_t ws_size, hipStream_t stream) {
  (void)in_sizes; (void)n_in; (void)out_size; (void)ws_size;
  const float* nf = (const float*)d_in[0];
  const float* ef = (const float*)d_in[1];
  const float* ea = (const float*)d_in[2];
  const int* nlist = (const int*)d_in[3];
  const int* nvalid = (const int*)d_in[4];
  const float* W_edge = (const float*)d_in[5];
  const float* b_edge = (const float*)d_in[6];
  const float* W_node = (const float*)d_in[7];
  const float* b_node = (const float*)d_in[8];
  const float* W_msg = (const float*)d_in[9];
  const float* b_msg = (const float*)d_in[10];
  const float* W_qkv = (const float*)d_in[11];
  const float* b_qkv = (const float*)d_in[12];
  const float* W_out = (const float*)d_in[13];
  const float* b_out = (const float*)d_in[14];
  const float* g_attn = (const float*)d_in[15];
  const float* be_attn = (const float*)d_in[16];
  const float* g_fn = (const float*)d_in[17];
  const float* be_fn = (const float*)d_in[18];
  const float* g_fe = (const float*)d_in[19];
  const float* be_fe = (const float*)d_in[20];
  const float* Wn1 = (const float*)d_in[21];
  const float* bn1 = (const float*)d_in[22];
  const float* Wn2 = (const float*)d_in[23];
  const float* bn2 = (const float*)d_in[24];
  const float* We1 = (const float*)d_in[25];
  const float* be1 = (const float*)d_in[26];
  const float* We2 = (const float*)d_in[27];
  const float* be2 = (const float*)d_in[28];

  float* ws0 = (float*)d_ws;                       // node_hidden [N,128]
  float* out_node = (float*)d_out;                 // [N,128] (holds node_res, then final)
  float* out_edge = out_node + (size_t)N_NODES * 128;  // [N,K,128]

  const int nb32 = (N_NODES + 31) / 32;
  ln_in_kernel<<<nb32, 256, 0, stream>>>(nf, g_attn, be_attn, ws0);
  egab_main<<<N_NODES, 256, 0, stream>>>(
      nf, ef, ea, nlist, nvalid, W_edge, b_edge, W_node, b_node, W_msg, b_msg,
      W_qkv, b_qkv, W_out, b_out, g_fe, be_fe, We1, be1, We2, be2, ws0,
      out_node, out_edge);
  node_ffn_kernel<<<nb32, 256, 0, stream>>>(out_node, g_fn, be_fn, Wn1, bn1,
                                            Wn2, bn2, out_node);
}

// Round 2
// 989.622 us; speedup vs baseline: 3.7322x; 3.7322x over previous
//
#include <hip/hip_runtime.h>
#include <cstddef>

#define N_NODES 10000
#define KNBR 32
#define HDIM 128
#define NHEADS 8

using short8 = __attribute__((ext_vector_type(8))) short;
using short4v = __attribute__((ext_vector_type(4))) short;
using f32x4 = __attribute__((ext_vector_type(4))) float;

__device__ __forceinline__ f32x4 mfma16(short8 a, short8 b, f32x4 c) {
  return __builtin_amdgcn_mfma_f32_16x16x32_bf16(a, b, c, 0, 0, 0);
}

__device__ __forceinline__ short f2bf(float f) {
  unsigned u = __builtin_bit_cast(unsigned, f);
  unsigned r = (u + 0x7fffu + ((u >> 16) & 1u)) >> 16;
  return (short)r;
}
__device__ __forceinline__ float bf2f(short s) {
  unsigned u = ((unsigned)(unsigned short)s) << 16;
  return __builtin_bit_cast(float, u);
}

// tanh-approximate gelu, matching jax.nn.gelu(approximate=True)
__device__ __forceinline__ float gelu_f(float x) {
  float a = 0.7978845608028654f * fmaf(0.044715f * x, x * x, x);
  float e = __expf(2.0f * a);
  return 0.5f * x * (2.0f - 2.0f / (e + 1.0f));
}

// Swizzled LDS tiles: row-major [rows][128 or 256] bf16, 16B chunk c of row r
// stored at physical chunk (c ^ (r&7)). Gives conflict-free A-frag ds_read_b128.
__device__ __forceinline__ short8 ld_sw128(const short* b, int r, int ch) {
  return *(const short8*)(b + r * 128 + (((ch ^ (r & 7))) << 3));
}
__device__ __forceinline__ short8 ld_sw256(const short* b, int r, int ch) {
  return *(const short8*)(b + r * 256 + (((ch ^ (r & 7))) << 3));
}
__device__ __forceinline__ void st_sw128(short* b, int r, int col, short v) {
  b[r * 128 + ((((col >> 3) ^ (r & 7))) << 3) + (col & 7)] = v;
}
__device__ __forceinline__ void st_sw256(short* b, int r, int col, short v) {
  b[r * 256 + ((((col >> 3) ^ (r & 7))) << 3) + (col & 7)] = v;
}

// Per-wave MFMA GEMM: A (via aload lambda) [16*MT x 32*KS] bf16, B = Wt slice
// [16*NT rows][32*KS] bf16 row-major (i.e. W transposed), C via epi(mt,nt,acc).
// C layout: col = n-tile base + (lane&15), row = mt*16 + (lane>>4)*4 + reg.
template <int MT, int NT, int KS, typename ALoad, typename Epi>
__device__ __forceinline__ void wgemm(ALoad aload, const short* __restrict__ Bt,
                                      Epi epi) {
  const int lane = threadIdx.x & 63;
  const int lm = lane & 15, lq = lane >> 4;
  short8 a[MT][KS];
#pragma unroll
  for (int mt = 0; mt < MT; ++mt)
#pragma unroll
    for (int k = 0; k < KS; ++k) a[mt][k] = aload(mt * 16 + lm, k, lq);
#pragma unroll
  for (int nt = 0; nt < NT; ++nt) {
    short8 b[KS];
#pragma unroll
    for (int k = 0; k < KS; ++k)
      b[k] = *(const short8*)(Bt + (nt * 16 + lm) * (KS * 32) + k * 32 + lq * 8);
#pragma unroll
    for (int mt = 0; mt < MT; ++mt) {
      f32x4 acc = {0.f, 0.f, 0.f, 0.f};
#pragma unroll
      for (int k = 0; k < KS; ++k) acc = mfma16(a[mt][k], b[k], acc);
      epi(mt, nt, acc);
    }
  }
}

// ---------------- kernel 0: weights -> bf16 transposed in ws ----------------
struct WSrc { const float* p[9]; };

__global__ void wprep_kernel(WSrc ws, short* __restrict__ dst) {
  const int cum[10] = {0, 16384, 49152, 81920, 131072, 147456, 180224, 212992, 245760, 278528};
  const int Ks[9] = {128, 256, 256, 128, 128, 128, 256, 128, 256};
  const int Ns[9] = {128, 128, 128, 384, 128, 256, 128, 256, 128};
  int eg = blockIdx.x * 256 + threadIdx.x;
  int id = 0;
#pragma unroll
  for (int i = 0; i < 8; ++i) id += (eg >= cum[i + 1]) ? 1 : 0;
  int e = eg - cum[id];
  int K = Ks[id];
  int n = (K == 128) ? (e >> 7) : (e >> 8);
  int k = e - n * K;
  dst[eg] = f2bf(ws.p[id][k * Ns[id] + n]);
}

// ---------------- kernel 1: LN(node_features) -> bf16 ws0 ----------------
__global__ __launch_bounds__(256) void ln_in_kernel(
    const float* __restrict__ in, const float* __restrict__ g,
    const float* __restrict__ be, short* __restrict__ out) {
  __shared__ float scr[32 * 8 * 2 + 64];
  const int tid = threadIdx.x;
  const int r = tid >> 3, j = tid & 7;
  const int base = blockIdx.x * 32;
  const int rg = base + r;
  const bool valid = rg < N_NODES;
  float4 v[4];
#pragma unroll
  for (int i = 0; i < 4; ++i)
    v[i] = valid ? ((const float4*)(in + (size_t)rg * 128 + j * 16))[i]
                 : make_float4(0.f, 0.f, 0.f, 0.f);
  float s = 0.f, s2 = 0.f;
#pragma unroll
  for (int i = 0; i < 4; ++i) {
    s += v[i].x + v[i].y + v[i].z + v[i].w;
    s2 = fmaf(v[i].x, v[i].x, s2); s2 = fmaf(v[i].y, v[i].y, s2);
    s2 = fmaf(v[i].z, v[i].z, s2); s2 = fmaf(v[i].w, v[i].w, s2);
  }
  scr[r * 8 + j] = s;
  scr[256 + r * 8 + j] = s2;
  __syncthreads();
  if (tid < 32) {
    float ss = 0.f, q2 = 0.f;
#pragma unroll
    for (int i = 0; i < 8; ++i) { ss += scr[tid * 8 + i]; q2 += scr[256 + tid * 8 + i]; }
    float mn = ss * (1.f / 128.f);
    float vr = fmaf(-mn, mn, q2 * (1.f / 128.f));
    scr[512 + tid] = mn;
    scr[544 + tid] = rsqrtf(vr + 1e-5f);
  }
  __syncthreads();
  if (!valid) return;
  float mn = scr[512 + r], rs = scr[544 + r];
  short8 o[2];
#pragma unroll
  for (int i = 0; i < 4; ++i) {
    int c0 = j * 16 + i * 4;
    float4 gg = *(const float4*)(g + c0);
    float4 bb = *(const float4*)(be + c0);
    float* vf = (float*)&v[i];
    float* gf = (float*)&gg;
    float* bf = (float*)&bb;
#pragma unroll
    for (int e = 0; e < 4; ++e)
      o[i >> 1][(i & 1) * 4 + e] = f2bf(fmaf((vf[e] - mn) * rs, gf[e], bf[e]));
  }
  *(short8*)(out + (size_t)rg * 128 + j * 16) = o[0];
  *(short8*)(out + (size_t)rg * 128 + j * 16 + 8) = o[1];
}

// ---------------- kernel 2: fused per-node-pair block (MFMA) ----------------
__global__ __launch_bounds__(256, 2) void egab_main(
    const float* __restrict__ nf, const float* __restrict__ ef,
    const float* __restrict__ ea, const int* __restrict__ nlist,
    const int* __restrict__ nvalid,
    const float* __restrict__ b_edge, const float* __restrict__ b_node,
    const float* __restrict__ b_msg, const float* __restrict__ b_qkv,
    const float* __restrict__ b_out, const float* __restrict__ g_fe,
    const float* __restrict__ be_fe, const float* __restrict__ be1,
    const float* __restrict__ be2,
    const short* __restrict__ WtE, const short* __restrict__ WtN,
    const short* __restrict__ WtM, const short* __restrict__ WtQ,
    const short* __restrict__ WtO, const short* __restrict__ WtE1,
    const short* __restrict__ WtE2, const short* __restrict__ nh_bf,
    float* __restrict__ out_node, float* __restrict__ out_edge) {
  // 64KB LDS pool: four 16KB regions, lifetime-aliased:
  // R0: EA -> MS -> CX -> EHN ; R1: NB -> QH(+P) -> R(res bf16)
  // R2: EH -> KH(+P) -> LNscr -> HID.lo ; R3: NH -> VT -> HID.hi
  __shared__ short lds[32768];
  short* R0 = lds;
  short* R1 = lds + 8192;
  short* R2 = lds + 16384;
  short* R3 = lds + 24576;

  const int tid = threadIdx.x;
  const int w = tid >> 6;
  const int lane = tid & 63;
  const int lm = lane & 15, lq = lane >> 4;
  const int base = blockIdx.x * 2;  // 2 nodes per block
  const int n0 = w * 32;            // wave col slice for Nout=128 GEMMs

  // ---- S1: edge_attr -> EA(R0) bf16 swizzled; gather neighbors -> NB(R1) ----
  {
    const float* eap = ea + (size_t)base * 4096;
    int r = tid >> 2;
    int c0 = (tid & 3) * 32;
#pragma unroll
    for (int j = 0; j < 4; ++j) {
      float4 fa = ((const float4*)eap)[tid * 8 + j * 2];
      float4 fb = ((const float4*)eap)[tid * 8 + j * 2 + 1];
      short8 v = {f2bf(fa.x), f2bf(fa.y), f2bf(fa.z), f2bf(fa.w),
                  f2bf(fb.x), f2bf(fb.y), f2bf(fb.z), f2bf(fb.w)};
      int ch = (c0 >> 3) + j;
      *(short8*)(R0 + r * 128 + ((ch ^ (r & 7)) << 3)) = v;
    }
    int rr = tid >> 2, sg = tid & 3;
    int idx = nlist[(base + (rr >> 5)) * KNBR + (rr & 31)];
    const short* srow = nh_bf + (size_t)idx * 128;
#pragma unroll
    for (int j = 0; j < 4; ++j) {
      int ch = sg * 4 + j;
      short8 v = *(const short8*)(srow + ch * 8);
      *(short8*)(R1 + rr * 128 + ((ch ^ (rr & 7)) << 3)) = v;
    }
  }
  __syncthreads();

  // ---- S2: edge_hidden = gelu(EA @ WtE) -> EH(R2);
  //          node_hid = gelu([center|NB] @ WtN) -> NH(R3) ----
  wgemm<4, 2, 4>(
      [&](int r, int k, int q) { return ld_sw128(R0, r, k * 4 + q); },
      WtE + (size_t)n0 * 128,
      [&](int mt, int nt, f32x4 acc) {
        int col = n0 + nt * 16 + lm;
        float bb = b_edge[col];
#pragma unroll
        for (int rr = 0; rr < 4; ++rr)
          st_sw128(R2, mt * 16 + lq * 4 + rr, col, f2bf(gelu_f(acc[rr] + bb)));
      });
  wgemm<4, 2, 8>(
      [&](int r, int k, int q) {
        if (k < 4)  // center row (broadcast per node) straight from global bf16
          return *(const short8*)(nh_bf + (size_t)(base + (r >> 5)) * 128 +
                                  k * 32 + q * 8);
        return ld_sw128(R1, r, (k - 4) * 4 + q);
      },
      WtN + (size_t)n0 * 256,
      [&](int mt, int nt, f32x4 acc) {
        int col = n0 + nt * 16 + lm;
        float bb = b_node[col];
#pragma unroll
        for (int rr = 0; rr < 4; ++rr)
          st_sw128(R3, mt * 16 + lq * 4 + rr, col, f2bf(gelu_f(acc[rr] + bb)));
      });
  __syncthreads();

  // ---- S3: msg = gelu([EH|NH] @ WtM) -> MS(R0) ----
  wgemm<4, 2, 8>(
      [&](int r, int k, int q) {
        if (k < 4) return ld_sw128(R2, r, k * 4 + q);
        return ld_sw128(R3, r, (k - 4) * 4 + q);
      },
      WtM + (size_t)n0 * 256,
      [&](int mt, int nt, f32x4 acc) {
        int col = n0 + nt * 16 + lm;
        float bb = b_msg[col];
#pragma unroll
        for (int rr = 0; rr < 4; ++rr)
          st_sw128(R0, mt * 16 + lq * 4 + rr, col, f2bf(gelu_f(acc[rr] + bb)));
      });
  __syncthreads();

  // ---- S4: qkv = MS @ WtQ ; q -> QH(R1) [2][8][32][16], k -> KH(R2),
  //          v -> VT(R3) [2][128 rows=h*16+d][32 m] chunk-swizzled ----
  {
    const int q0 = w * 96;
    wgemm<4, 6, 4>(
        [&](int r, int k, int q) { return ld_sw128(R0, r, k * 4 + q); },
        WtQ + (size_t)q0 * 128,
        [&](int mt, int nt, f32x4 acc) {
          int c = q0 + nt * 16;  // tile-uniform global col base
          float bb = b_qkv[c + lm];
          int ni = mt >> 1;
          int m32b = (mt & 1) * 16 + lq * 4;
          if (c < 256) {
            short* dst = (c < 128 ? R1 + ((ni * 8 + (c >> 4)) * 32) * 16
                                  : R2 + ((ni * 8 + ((c - 128) >> 4)) * 32) * 16);
#pragma unroll
            for (int rr = 0; rr < 4; ++rr)
              dst[(m32b + rr) * 16 + lm] = f2bf(acc[rr] + bb);
          } else {
            int rv = (c - 256) + lm;  // v column 0..127 -> VT row
            short4v pv;
#pragma unroll
            for (int rr = 0; rr < 4; ++rr) pv[rr] = f2bf(acc[rr] + bb);
            int chv = m32b >> 3;
            *(short4v*)(R3 + ni * 4096 + rv * 32 + ((chv ^ (rv & 3)) << 3) +
                        (m32b & 7)) = pv;
          }
        });
  }
  __syncthreads();

  // ---- S5: 8-head attention, one (node,head) instance per wave-iter ----
  {
    const short8 zz = {0, 0, 0, 0, 0, 0, 0, 0};
    const f32x4 z4 = {0.f, 0.f, 0.f, 0.f};
#pragma unroll
    for (int it = 0; it < 4; ++it) {
      int inst = (it << 2) | w;
      int ni = inst >> 3, h = inst & 7;
      int nvv = nvalid[base + ni];
      short* qh = R1 + inst * 512;
      short* kh = R2 + inst * 512;
      short8 bk[2];
#pragma unroll
      for (int nt = 0; nt < 2; ++nt)
        bk[nt] = (lq < 2) ? *(const short8*)(kh + (nt * 16 + lm) * 16 + lq * 8) : zz;
      float sc[2][2][4];
#pragma unroll
      for (int mt = 0; mt < 2; ++mt) {
        short8 aq = (lq < 2) ? *(const short8*)(qh + (mt * 16 + lm) * 16 + lq * 8) : zz;
#pragma unroll
        for (int nt = 0; nt < 2; ++nt) {
          f32x4 s = mfma16(aq, bk[nt], z4);
#pragma unroll
          for (int rr = 0; rr < 4; ++rr) {
            float x = s[rr] * 0.25f;
            if (nt * 16 + lm >= nvv) x = -1e9f;
            sc[mt][nt][rr] = x;
          }
        }
      }
      // softmax per row (row = mt*16 + lq*4 + rr, cols distributed over lm)
#pragma unroll
      for (int mt = 0; mt < 2; ++mt)
#pragma unroll
        for (int rr = 0; rr < 4; ++rr) {
          float x0 = sc[mt][0][rr], x1 = sc[mt][1][rr];
          float mx = fmaxf(x0, x1);
          mx = fmaxf(mx, __shfl_xor(mx, 1, 16));
          mx = fmaxf(mx, __shfl_xor(mx, 2, 16));
          mx = fmaxf(mx, __shfl_xor(mx, 4, 16));
          mx = fmaxf(mx, __shfl_xor(mx, 8, 16));
          float e0 = __expf(x0 - mx), e1 = __expf(x1 - mx);
          float sm = e0 + e1;
          sm += __shfl_xor(sm, 1, 16);
          sm += __shfl_xor(sm, 2, 16);
          sm += __shfl_xor(sm, 4, 16);
          sm += __shfl_xor(sm, 8, 16);
          float ri = 1.f / sm;
          int row = mt * 16 + lq * 4 + rr;
          qh[row * 16 + lm] = f2bf(e0 * ri);  // P cols 0-15 (own instance slice)
          kh[row * 16 + lm] = f2bf(e1 * ri);  // P cols 16-31
        }
      // PV: A = P (K=32), B = VT head rows -> ctx into CX(R0)
#pragma unroll
      for (int mt = 0; mt < 2; ++mt) {
        const short* psrc = (lq < 2) ? qh : kh;
        short8 pa = *(const short8*)(psrc + (mt * 16 + lm) * 16 + (lq & 1) * 8);
        int rv = h * 16 + lm;
        short8 vb = *(const short8*)(R3 + ni * 4096 + rv * 32 + ((lq ^ (rv & 3)) << 3));
        f32x4 c = mfma16(pa, vb, z4);
#pragma unroll
        for (int rr = 0; rr < 4; ++rr)
          st_sw128(R0, ni * 32 + mt * 16 + lq * 4 + rr, h * 16 + lm, f2bf(c[rr]));
      }
    }
  }
  __syncthreads();

  // ---- S6: edge_out = CX @ WtO + b_out; R(R1) = edge_out + ef (bf16);
  //          node_res = sum_{k<nv} edge_out + nf -> out_node ----
  {
    int nv0 = nvalid[base], nv1 = nvalid[base + 1];
    float nsum[2][2] = {{0.f, 0.f}, {0.f, 0.f}};
    wgemm<4, 2, 4>(
        [&](int r, int k, int q) { return ld_sw128(R0, r, k * 4 + q); },
        WtO + (size_t)n0 * 128,
        [&](int mt, int nt, f32x4 acc) {
          int col = n0 + nt * 16 + lm;
          float bb = b_out[col];
          int ni = mt >> 1;
          int nvv = ni ? nv1 : nv0;
#pragma unroll
          for (int rr = 0; rr < 4; ++rr) {
            int kk = (mt & 1) * 16 + lq * 4 + rr;
            float eo = acc[rr] + bb;
            if (kk < nvv) nsum[nt][ni] += eo;
            float efv = ef[((size_t)(base + ni) * KNBR + kk) * 128 + col];
            st_sw128(R1, mt * 16 + lq * 4 + rr, col, f2bf(eo + efv));
          }
        });
#pragma unroll
    for (int nt = 0; nt < 2; ++nt)
#pragma unroll
      for (int ni = 0; ni < 2; ++ni) {
        float v = nsum[nt][ni];
        v += __shfl_xor(v, 16, 64);
        v += __shfl_xor(v, 32, 64);
        if (lq == 0) {
          int col = n0 + nt * 16 + lm;
          out_node[(size_t)(base + ni) * 128 + col] =
              v + nf[(size_t)(base + ni) * 128 + col];
        }
      }
  }
  __syncthreads();

  // ---- S7: EHN(R0) = LayerNorm(R) (scratch in R2) ----
  {
    float* scr = (float*)R2;
    int r = tid >> 2, sg = tid & 3;
    short8 xv[4];
    float s = 0.f, s2 = 0.f;
#pragma unroll
    for (int j = 0; j < 4; ++j) {
      int ch = sg * 4 + j;
      xv[j] = *(const short8*)(R1 + r * 128 + ((ch ^ (r & 7)) << 3));
#pragma unroll
      for (int e = 0; e < 8; ++e) {
        float x = bf2f(xv[j][e]);
        s += x;
        s2 = fmaf(x, x, s2);
      }
    }
    scr[r * 4 + sg] = s;
    scr[256 + r * 4 + sg] = s2;
    __syncthreads();
    if (tid < 64) {
      float ss = scr[tid * 4] + scr[tid * 4 + 1] + scr[tid * 4 + 2] + scr[tid * 4 + 3];
      float q2 = scr[256 + tid * 4] + scr[256 + tid * 4 + 1] +
                 scr[256 + tid * 4 + 2] + scr[256 + tid * 4 + 3];
      float mn = ss * (1.f / 128.f);
      float vr = fmaf(-mn, mn, q2 * (1.f / 128.f));
      scr[512 + tid * 2] = mn;
      scr[512 + tid * 2 + 1] = rsqrtf(vr + 1e-5f);
    }
    __syncthreads();
    float mn = scr[512 + r * 2], rs = scr[512 + r * 2 + 1];
#pragma unroll
    for (int j = 0; j < 4; ++j) {
      int ch = sg * 4 + j;
      int c0 = ch * 8;
      float4 g0 = *(const float4*)(g_fe + c0);
      float4 g1 = *(const float4*)(g_fe + c0 + 4);
      float4 b0 = *(const float4*)(be_fe + c0);
      float4 b1 = *(const float4*)(be_fe + c0 + 4);
      const float* gp0 = (const float*)&g0;
      const float* gp1 = (const float*)&g1;
      const float* bp0 = (const float*)&b0;
      const float* bp1 = (const float*)&b1;
      short8 ov;
#pragma unroll
      for (int e = 0; e < 4; ++e) {
        ov[e] = f2bf(fmaf((bf2f(xv[j][e]) - mn) * rs, gp0[e], bp0[e]));
        ov[4 + e] = f2bf(fmaf((bf2f(xv[j][4 + e]) - mn) * rs, gp1[e], bp1[e]));
      }
      *(short8*)(R0 + r * 128 + ((ch ^ (r & 7)) << 3)) = ov;
    }
  }
  __syncthreads();

  // ---- S8: HID(R2..R3) = gelu(EHN @ WtE1 + be1), [64][256] swizzled ----
  {
    const int f0 = w * 64;
    wgemm<4, 4, 4>(
        [&](int r, int k, int q) { return ld_sw128(R0, r, k * 4 + q); },
        WtE1 + (size_t)f0 * 128,
        [&](int mt, int nt, f32x4 acc) {
          int col = f0 + nt * 16 + lm;
          float bb = be1[col];
#pragma unroll
          for (int rr = 0; rr < 4; ++rr)
            st_sw256(R2, mt * 16 + lq * 4 + rr, col, f2bf(gelu_f(acc[rr] + bb)));
        });
  }
  __syncthreads();

  // ---- S9: out_edge = R + HID @ WtE2 + be2 (fp32 global stores) ----
  wgemm<4, 2, 8>(
      [&](int r, int k, int q) { return ld_sw256(R2, r, k * 4 + q); },
      WtE2 + (size_t)n0 * 256,
      [&](int mt, int nt, f32x4 acc) {
        int col = n0 + nt * 16 + lm;
        float bb = be2[col];
        int ni = mt >> 1;
#pragma unroll
        for (int rr = 0; rr < 4; ++rr) {
          int m = mt * 16 + lq * 4 + rr;
          int kk = m & 31;
          float rv = bf2f(R1[m * 128 + ((((col >> 3) ^ (m & 7))) << 3) + (col & 7)]);
          out_edge[((size_t)(base + ni) * KNBR + kk) * 128 + col] = rv + acc[rr] + bb;
        }
      });
}

// ---------------- kernel 3: node FFN (64 nodes/block, MFMA) ----------------
__global__ __launch_bounds__(256) void node_ffn_kernel(
    const float* __restrict__ nres, const float* __restrict__ g,
    const float* __restrict__ be, const short* __restrict__ WtN1,
    const float* __restrict__ bn1, const short* __restrict__ WtN2,
    const float* __restrict__ bn2, float* __restrict__ out) {
  __shared__ short lds[32768];
  short* EHN = lds;               // [64][128] swizzled bf16
  float* scr = (float*)(lds + 8192);
  short* HID = lds + 16384;       // [64][256] swizzled bf16

  const int tid = threadIdx.x;
  const int w = tid >> 6;
  const int lane = tid & 63;
  const int lm = lane & 15, lq = lane >> 4;
  const int base = blockIdx.x * 64;
  const int n0 = w * 32;

  // LN from global node_res (fp32) -> EHN
  {
    int r = tid >> 2, sg = tid & 3;
    bool valid = (base + r) < N_NODES;
    float xf[32];
#pragma unroll
    for (int i = 0; i < 8; ++i) {
      float4 v = valid ? ((const float4*)(nres + (size_t)(base + r) * 128 + sg * 32))[i]
                       : make_float4(0.f, 0.f, 0.f, 0.f);
      xf[i * 4] = v.x; xf[i * 4 + 1] = v.y; xf[i * 4 + 2] = v.z; xf[i * 4 + 3] = v.w;
    }
    float s = 0.f, s2 = 0.f;
#pragma unroll
    for (int i = 0; i < 32; ++i) { s += xf[i]; s2 = fmaf(xf[i], xf[i], s2); }
    scr[r * 4 + sg] = s;
    scr[256 + r * 4 + sg] = s2;
    __syncthreads();
    if (tid < 64) {
      float ss = scr[tid * 4] + scr[tid * 4 + 1] + scr[tid * 4 + 2] + scr[tid * 4 + 3];
      float q2 = scr[256 + tid * 4] + scr[256 + tid * 4 + 1] +
                 scr[256 + tid * 4 + 2] + scr[256 + tid * 4 + 3];
      float mn = ss * (1.f / 128.f);
      float vr = fmaf(-mn, mn, q2 * (1.f / 128.f));
      scr[512 + tid * 2] = mn;
      scr[512 + tid * 2 + 1] = rsqrtf(vr + 1e-5f);
    }
    __syncthreads();
    float mn = scr[512 + r * 2], rs = scr[512 + r * 2 + 1];
#pragma unroll
    for (int j = 0; j < 4; ++j) {
      int ch = sg * 4 + j;
      int c0 = ch * 8;
      short8 ov;
#pragma unroll
      for (int e = 0; e < 8; ++e)
        ov[e] = f2bf(fmaf((xf[j * 8 + e] - mn) * rs, g[c0 + e], be[c0 + e]));
      *(short8*)(EHN + r * 128 + ((ch ^ (r & 7)) << 3)) = ov;
    }
  }
  __syncthreads();

  // hidden = gelu(EHN @ WtN1 + bn1)
  {
    const int f0 = w * 64;
    wgemm<4, 4, 4>(
        [&](int r, int k, int q) { return ld_sw128(EHN, r, k * 4 + q); },
        WtN1 + (size_t)f0 * 128,
        [&](int mt, int nt, f32x4 acc) {
          int col = f0 + nt * 16 + lm;
          float bb = bn1[col];
#pragma unroll
          for (int rr = 0; rr < 4; ++rr)
            st_sw256(HID, mt * 16 + lq * 4 + rr, col, f2bf(gelu_f(acc[rr] + bb)));
        });
  }
  __syncthreads();

  // out = node_res + hidden @ WtN2 + bn2
  wgemm<4, 2, 8>(
      [&](int r, int k, int q) { return ld_sw256(HID, r, k * 4 + q); },
      WtN2 + (size_t)n0 * 256,
      [&](int mt, int nt, f32x4 acc) {
        int col = n0 + nt * 16 + lm;
        float bb = bn2[col];
#pragma unroll
        for (int rr = 0; rr < 4; ++rr) {
          int m = mt * 16 + lq * 4 + rr;
          if (base + m < N_NODES) {
            float rv = nres[(size_t)(base + m) * 128 + col];
            out[(size_t)(base + m) * 128 + col] = rv + acc[rr] + bb;
          }
        }
      });
}

// ---------------- launch ----------------
extern "C" void kernel_launch(void* const* d_in, const int* in_sizes, int n_in,
                              void* d_out, int out_size, void* d_ws,
                              size_t ws_size, hipStream_t stream) {
  (void)in_sizes; (void)n_in; (void)out_size; (void)ws_size;
  const float* nf = (const float*)d_in[0];
  const float* ef = (const float*)d_in[1];
  const float* ea = (const float*)d_in[2];
  const int* nlist = (const int*)d_in[3];
  const int* nvalid = (const int*)d_in[4];
  const float* W_edge = (const float*)d_in[5];
  const float* b_edge = (const float*)d_in[6];
  const float* W_node = (const float*)d_in[7];
  const float* b_node = (const float*)d_in[8];
  const float* W_msg = (const float*)d_in[9];
  const float* b_msg = (const float*)d_in[10];
  const float* W_qkv = (const float*)d_in[11];
  const float* b_qkv = (const float*)d_in[12];
  const float* W_out = (const float*)d_in[13];
  const float* b_out = (const float*)d_in[14];
  const float* g_attn = (const float*)d_in[15];
  const float* be_attn = (const float*)d_in[16];
  const float* g_fn = (const float*)d_in[17];
  const float* be_fn = (const float*)d_in[18];
  const float* g_fe = (const float*)d_in[19];
  const float* be_fe = (const float*)d_in[20];
  const float* Wn1 = (const float*)d_in[21];
  const float* bn1 = (const float*)d_in[22];
  const float* Wn2 = (const float*)d_in[23];
  const float* bn2 = (const float*)d_in[24];
  const float* We1 = (const float*)d_in[25];
  const float* be1 = (const float*)d_in[26];
  const float* We2 = (const float*)d_in[27];
  const float* be2 = (const float*)d_in[28];

  short* ws0 = (short*)d_ws;           // node_hidden bf16 [N][128]
  short* wsW = ws0 + 1280000;          // transposed bf16 weights, 278528 elems
  short* WtE = wsW;
  short* WtN = wsW + 16384;
  short* WtM = wsW + 49152;
  short* WtQ = wsW + 81920;
  short* WtO = wsW + 131072;
  short* WtE1 = wsW + 147456;
  short* WtE2 = wsW + 180224;
  short* WtN1 = wsW + 212992;
  short* WtN2 = wsW + 245760;

  float* out_node = (float*)d_out;
  float* out_edge = out_node + (size_t)N_NODES * 128;

  WSrc wsrc;
  wsrc.p[0] = W_edge; wsrc.p[1] = W_node; wsrc.p[2] = W_msg;
  wsrc.p[3] = W_qkv;  wsrc.p[4] = W_out;  wsrc.p[5] = We1;
  wsrc.p[6] = We2;    wsrc.p[7] = Wn1;    wsrc.p[8] = Wn2;

  wprep_kernel<<<1088, 256, 0, stream>>>(wsrc, wsW);
  ln_in_kernel<<<(N_NODES + 31) / 32, 256, 0, stream>>>(nf, g_attn, be_attn, ws0);
  egab_main<<<N_NODES / 2, 256, 0, stream>>>(
      nf, ef, ea, nlist, nvalid, b_edge, b_node, b_msg, b_qkv, b_out, g_fe,
      be_fe, be1, be2, WtE, WtN, WtM, WtQ, WtO, WtE1, WtE2, ws0, out_node,
      out_edge);
  node_ffn_kernel<<<(N_NODES + 63) / 64, 256, 0, stream>>>(
      out_node, g_fn, be_fn, WtN1, bn1, WtN2, bn2, out_node);
}